// Round 10
// baseline (370.310 us; speedup 1.0000x reference)
//
#include <hip/hip_runtime.h>
#include <math.h>

#define NMOL 256
#define NATOM 384
#define NN (NMOL*NATOM)          // 98304
#define A0C  0.529177249f
#define A0_INV (1.0f/0.529177249f)

typedef short bf16x8 __attribute__((ext_vector_type(8)));
typedef float f32x4  __attribute__((ext_vector_type(4)));

__constant__ float c_sigma[8] = {0.5515909f, 1.8886297f, 1.3225029f, 1.2316629f,
                                 2.1884933f, 1.7750372f, 1.3677907f, 1.3820058f};

__device__ __forceinline__ short f2b(float f) {           // f32 -> bf16 RNE
    unsigned u = __float_as_uint(f);
    u = (u + 0x7fffu + ((u >> 16) & 1u)) >> 16;
    return (short)u;
}
__device__ __forceinline__ float b2f(short s) {
    return __uint_as_float(((unsigned)(unsigned short)s) << 16);
}
// cheap celu(alpha=0.1): 0.1*(e^(10v)-1) = 0.1*exp2(10v*log2e)-0.1
__device__ __forceinline__ float celu01(float v) {
    float e = __builtin_amdgcn_exp2f(v * 14.426950408889634f);
    return v > 0.f ? v : fmaf(0.1f, e, -0.1f);
}
__device__ __forceinline__ bf16x8 cvt8(f32x4 a, f32x4 b) {
    bf16x8 r;
    r[0] = f2b(a.x); r[1] = f2b(a.y); r[2] = f2b(a.z); r[3] = f2b(a.w);
    r[4] = f2b(b.x); r[5] = f2b(b.y); r[6] = f2b(b.z); r[7] = f2b(b.w);
    return r;
}

// fast erf (x>=0): Abramowitz-Stegun 7.1.26, |abs err| <= 1.5e-7
__device__ __forceinline__ float erf_fast(float x) {
    float t = __builtin_amdgcn_rcpf(fmaf(0.3275911f, x, 1.0f));
    float p = fmaf(t, 1.061405429f, -1.453152027f);
    p = fmaf(t, p, 1.421413741f);
    p = fmaf(t, p, -0.284496736f);
    p = fmaf(t, p, 0.254829592f);
    p = p * t;
    float e = __builtin_amdgcn_exp2f(-x * x * 1.4426950408889634f);
    return fmaf(-p, e, 1.0f);
}

// ======================= GEMM0: h1p = aev @ W1a^T + b1 =======================
template<int N, int K>
__global__ __launch_bounds__(256, 4)
void gemm0_k(const float* __restrict__ A, const short* __restrict__ Bw,
             const float* __restrict__ bias, short* __restrict__ Cout)
{
    constexpr int NK = K / 32;
    constexpr int NF = N / 32;
    constexpr int N2 = N / 2;
    constexpr int AROW = 40, BROW = 40;
    constexpr int ASZ = 64 * AROW;
    constexpr int BSZ = N * BROW;
    constexpr int AB  = 2 * ASZ + 2 * BSZ;
    constexpr int CSZ = 64 * N;
    constexpr int SM  = AB > CSZ ? AB : CSZ;
    constexpr int NB  = (N * 4 + 255) / 256;

    __shared__ short smem[SM];
    short* As0 = smem;
    short* As1 = smem + ASZ;
    short* Bs0 = smem + 2 * ASZ;
    short* Bs1 = smem + 2 * ASZ + BSZ;
    short* Cs  = smem;

    const int t    = threadIdx.x;
    const int lane = t & 63;
    const int wave = t >> 6;
    const int wm   = wave >> 1, wn = wave & 1;
    const int l15  = lane & 15, l4 = lane >> 4;
    const int m0   = blockIdx.x * 64;
    const int arow = t >> 2, aseg = t & 3;
    const float* a_f32 = A + ((size_t)m0 + arow) * K + aseg * 8;

    f32x4 af0, af1;
    bf16x8 br[NB];

    auto loadA = [&](int k0) {
        af0 = *(const f32x4*)(a_f32 + k0);
        af1 = *(const f32x4*)(a_f32 + k0 + 4);
    };
    auto loadB = [&](int k0) {
        #pragma unroll
        for (int ci = 0; ci < NB; ++ci) {
            int c = ci * 256 + t;
            if ((N * 4) % 256 == 0 || c < N * 4) {
                int row = c >> 2, half = c & 3;
                br[ci] = *(const bf16x8*)(Bw + (size_t)row * K + k0 + half * 8);
            }
        }
    };
    auto writeA = [&](short* dst) {
        *(bf16x8*)&dst[arow * AROW + aseg * 8] = cvt8(af0, af1);
    };
    auto writeB = [&](short* dst) {
        #pragma unroll
        for (int ci = 0; ci < NB; ++ci) {
            int c = ci * 256 + t;
            if ((N * 4) % 256 == 0 || c < N * 4) {
                int row = c >> 2, half = c & 3;
                *(bf16x8*)&dst[row * BROW + half * 8] = br[ci];
            }
        }
    };

    f32x4 acc[2][NF] = {};

    loadA(0); loadB(0);
    writeA(As0); writeB(Bs0);
    __syncthreads();

    int cur = 0;
    for (int ks = 0; ks < NK; ++ks) {
        if (ks + 1 < NK) { loadA((ks + 1) * 32); loadB((ks + 1) * 32); }
        short* Ac = cur ? As1 : As0;
        short* Bc = cur ? Bs1 : Bs0;
        bf16x8 a[2];
        #pragma unroll
        for (int mf = 0; mf < 2; ++mf)
            a[mf] = *(const bf16x8*)&Ac[(wm * 32 + mf * 16 + l15) * AROW + l4 * 8];
        #pragma unroll
        for (int nf = 0; nf < NF; ++nf) {
            bf16x8 b = *(const bf16x8*)&Bc[(wn * N2 + nf * 16 + l15) * BROW + l4 * 8];
            #pragma unroll
            for (int mf = 0; mf < 2; ++mf)
                acc[mf][nf] = __builtin_amdgcn_mfma_f32_16x16x32_bf16(a[mf], b, acc[mf][nf], 0, 0, 0);
        }
        if (ks + 1 < NK) {
            writeA(cur ? As0 : As1);
            writeB(cur ? Bs0 : Bs1);
            __syncthreads();
            cur ^= 1;
        }
    }
    __syncthreads();

    #pragma unroll
    for (int nf = 0; nf < NF; ++nf) {
        int col = wn * N2 + nf * 16 + l15;
        float bc = bias[col];
        #pragma unroll
        for (int mf = 0; mf < 2; ++mf)
            #pragma unroll
            for (int r = 0; r < 4; ++r)
                Cs[(wm * 32 + mf * 16 + l4 * 4 + r) * N + col] = f2b(acc[mf][nf][r] + bc);
    }
    __syncthreads();
    #pragma unroll
    for (int i = 0; i < NF; ++i) {
        int c = i * 256 + t;
        *(bf16x8*)(Cout + (size_t)m0 * N + c * 8) = *(const bf16x8*)&Cs[c * 8];
    }
}

// ======================= fused layers 2+3+4, frag-direct (r7 structure) =======================
// A and B fragments loaded straight from global (rank-2 + celu applied in regs);
// only the stage-1->2 transpose (H2) lives in LDS. 3 barriers total.
__global__ __launch_bounds__(256, 8)
void mlp23_kernel(const short* __restrict__ h1p, const short* __restrict__ W2b,
                  const float* __restrict__ b2, const short* __restrict__ W3b,
                  const float* __restrict__ b3, const float* __restrict__ W4,
                  const float* __restrict__ b4,
                  const float* __restrict__ qv, const float* __restrict__ espv,
                  const float* __restrict__ w1qp, const float* __restrict__ w1ep,
                  const int* __restrict__ species, float* __restrict__ chi)
{
    constexpr int K1 = 160, K2 = 128, N3 = 96;
    constexpr int H2ROW = 140;     // 280B stride -> ~2-way banks on b128 reads

    __shared__ short H2[64 * H2ROW];
    __shared__ float wq_s[K1], we_s[K1], w4_s[N3], b3_s[N3];
    __shared__ float chp[2][64];

    const int t    = threadIdx.x;
    const int lane = t & 63;
    const int wave = t >> 6;
    const int wm   = wave >> 1, wn = wave & 1;
    const int l15  = lane & 15, l4 = lane >> 4;
    const int m0   = blockIdx.x * 64;

    if (t < K1) { wq_s[t] = w1qp[t]; we_s[t] = w1ep[t]; }
    if (t < N3) { w4_s[t] = W4[t]; b3_s[t] = b3[t]; }

    // per-lane A-row constants (row = l15 within each mf group)
    int rowg[2];
    float qrow[2], erow[2];
    #pragma unroll
    for (int mf = 0; mf < 2; ++mf) {
        rowg[mf] = m0 + wm * 32 + mf * 16 + l15;
        qrow[mf] = qv[rowg[mf]];
        erow[mf] = espv[rowg[mf]];
    }
    __syncthreads();   // wq_s/we_s visible

    // ---- stage 1: celu(h1p + q*w1q + e*w1e) @ W2^T, K=160, no barriers ----
    f32x4 acc[2][4] = {};
    #pragma unroll
    for (int ks = 0; ks < 5; ++ks) {
        const int k0 = ks * 32 + l4 * 8;
        f32x4 wq0 = *(const f32x4*)&wq_s[k0];
        f32x4 wq1 = *(const f32x4*)&wq_s[k0 + 4];
        f32x4 we0 = *(const f32x4*)&we_s[k0];
        f32x4 we1 = *(const f32x4*)&we_s[k0 + 4];
        bf16x8 a[2];
        #pragma unroll
        for (int mf = 0; mf < 2; ++mf) {
            bf16x8 h = *(const bf16x8*)(h1p + (size_t)rowg[mf] * K1 + k0);
            #pragma unroll
            for (int j = 0; j < 4; ++j) {
                float v  = b2f(h[j])     + qrow[mf] * wq0[j] + erow[mf] * we0[j];
                float v2 = b2f(h[j + 4]) + qrow[mf] * wq1[j] + erow[mf] * we1[j];
                a[mf][j]     = f2b(celu01(v));
                a[mf][j + 4] = f2b(celu01(v2));
            }
        }
        #pragma unroll
        for (int nf = 0; nf < 4; ++nf) {
            bf16x8 b = *(const bf16x8*)(W2b + (size_t)(wn * 64 + nf * 16 + l15) * K1 + k0);
            #pragma unroll
            for (int mf = 0; mf < 2; ++mf)
                acc[mf][nf] = __builtin_amdgcn_mfma_f32_16x16x32_bf16(a[mf], b, acc[mf][nf], 0, 0, 0);
        }
    }

    // h2 tile -> LDS (celu applied)
    #pragma unroll
    for (int nf = 0; nf < 4; ++nf) {
        int col = wn * 64 + nf * 16 + l15;
        float bc = b2[col];
        #pragma unroll
        for (int mf = 0; mf < 2; ++mf)
            #pragma unroll
            for (int r = 0; r < 4; ++r)
                H2[(wm * 32 + mf * 16 + l4 * 4 + r) * H2ROW + col] =
                    f2b(celu01(acc[mf][nf][r] + bc));
    }
    __syncthreads();

    // ---- stage 2: H2 @ W3^T, K=128, B direct from global ----
    f32x4 acc2[2][3] = {};
    #pragma unroll
    for (int ks = 0; ks < 4; ++ks) {
        bf16x8 a[2];
        #pragma unroll
        for (int mf = 0; mf < 2; ++mf)
            a[mf] = *(const bf16x8*)&H2[(wm * 32 + mf * 16 + l15) * H2ROW + ks * 32 + l4 * 8];
        #pragma unroll
        for (int nf = 0; nf < 3; ++nf) {
            bf16x8 b = *(const bf16x8*)(W3b + (size_t)(wn * 48 + nf * 16 + l15) * K2 + ks * 32 + l4 * 8);
            #pragma unroll
            for (int mf = 0; mf < 2; ++mf)
                acc2[mf][nf] = __builtin_amdgcn_mfma_f32_16x16x32_bf16(a[mf], b, acc2[mf][nf], 0, 0, 0);
        }
    }

    // ---- chi epilogue: celu -> .W4 -> lane reduce -> softplus ----
    float val[2][4];
    #pragma unroll
    for (int mf = 0; mf < 2; ++mf)
        #pragma unroll
        for (int r = 0; r < 4; ++r) val[mf][r] = 0.f;
    #pragma unroll
    for (int nf = 0; nf < 3; ++nf) {
        int col = wn * 48 + nf * 16 + l15;
        float bc = b3_s[col];
        float wc = w4_s[col];
        #pragma unroll
        for (int mf = 0; mf < 2; ++mf)
            #pragma unroll
            for (int r = 0; r < 4; ++r)
                val[mf][r] += celu01(acc2[mf][nf][r] + bc) * wc;
    }
    #pragma unroll
    for (int off = 1; off < 16; off <<= 1)
        #pragma unroll
        for (int mf = 0; mf < 2; ++mf)
            #pragma unroll
            for (int r = 0; r < 4; ++r)
                val[mf][r] += __shfl_xor(val[mf][r], off, 64);
    if (l15 == 0) {
        #pragma unroll
        for (int mf = 0; mf < 2; ++mf)
            #pragma unroll
            for (int r = 0; r < 4; ++r)
                chp[wn][wm * 32 + mf * 16 + l4 * 4 + r] = val[mf][r];
    }
    __syncthreads();
    if (t < 64) {
        float s = chp[0][t] + chp[1][t] + b4[0];
        s = fmaxf(s, 0.f) + log1pf(expf(-fabsf(s)));   // softplus
        chi[m0 + t] = (species[m0 + t] != -1) ? s : 0.f;
    }
}

// ======= fused charge normalization + DIRECT ESP (no J matrix) =======
// DO_ESP: grid (NMOL, 4), block 384. Each block: charge-norm (redundant,
// cheap) -> full q vector in LDS -> thread (joff, iq) sums q_i*j_ij over a
// 96-i quarter for j = jt*96+joff -> 4 partials combined in LDS.
// !DO_ESP (final): grid (NMOL), writes output [species | q].
template<bool DO_ESP>
__global__ __launch_bounds__(384, 6)
void espd_kernel(const float* __restrict__ chi, const int* __restrict__ species,
                 const float* __restrict__ netq, const float* __restrict__ coords,
                 float* __restrict__ q, float* __restrict__ esp,
                 float* __restrict__ out)
{
    __shared__ float q_s[NATOM], msk_s[NATOM];
    __shared__ float cxs[NATOM], cys[NATOM], czs[NATOM], s2s[NATOM];
    __shared__ float part[NATOM];
    __shared__ float red_s[6], redc_s[6];

    const int m  = blockIdx.x, jt = blockIdx.y;
    const int t  = threadIdx.x;
    const int lane = t & 63, wv = t >> 6;
    const int idx = m * NATOM + t;

    float c = chi[idx];
    int sp = species[idx];
    float mk = (sp != -1) ? 1.f : 0.f;
    msk_s[t] = mk;
    if (DO_ESP) {
        cxs[t] = coords[(size_t)idx * 3 + 0];
        cys[t] = coords[(size_t)idx * 3 + 1];
        czs[t] = coords[(size_t)idx * 3 + 2];
        float sig = c_sigma[sp < 0 ? 7 : sp];
        s2s[t] = sig * sig;
    }
    // block reduce chi & mask
    float sc = c, sm = mk;
    #pragma unroll
    for (int off = 1; off < 64; off <<= 1) {
        sc += __shfl_xor(sc, off, 64);
        sm += __shfl_xor(sm, off, 64);
    }
    if (lane == 0) { red_s[wv] = sc; redc_s[wv] = sm; }
    __syncthreads();
    float chi_sum = red_s[0] + red_s[1] + red_s[2] + red_s[3] + red_s[4] + red_s[5];
    float na      = redc_s[0] + redc_s[1] + redc_s[2] + redc_s[3] + redc_s[4] + redc_s[5];
    float Q = netq[m];
    float k_net = 1.f + fabsf(Q) / chi_sum;
    float chi_mean = chi_sum / na;
    float k_p = (Q > 0.f) ? k_net : 1.f;
    float k_n = (Q < 0.f) ? k_net : 1.f;
    float qj = (-k_n * c + k_p * chi_mean) * mk;

    if (!DO_ESP) {
        out[idx]      = (float)sp;
        out[NN + idx] = qj;
        return;
    }

    q_s[t] = qj;
    if (jt == 0) q[idx] = qj;        // global q for next iteration's features
    __syncthreads();

    // ESP: j = jt*96 + joff, this thread sums i in [iq*96, iq*96+96)
    const int joff = t % 96;
    const int iq   = t / 96;
    const int jj   = jt * 96 + joff;
    const float rx = cxs[jj], ry = cys[jj], rz = czs[jj], s2j = s2s[jj];
    float acc = 0.f;
    const int i0 = iq * 96;
    #pragma unroll 4
    for (int i = i0; i < i0 + 96; ++i) {
        float dx = cxs[i] - rx, dy = cys[i] - ry, dz = czs[i] - rz;
        float d2 = fmaf(dx, dx, fmaf(dy, dy, dz * dz)) + 1e-16f;
        float rs = __builtin_amdgcn_rsqf(d2);
        float d  = d2 * rs * A0_INV;
        float ss = fmaxf(s2s[i] + s2j, 1e-8f);
        float x  = d * __builtin_amdgcn_rsqf(2.f * ss);
        float v  = erf_fast(x) * rs * A0C;
        acc += (i == jj) ? 0.f : q_s[i] * v;
    }
    part[t] = acc;
    __syncthreads();
    if (t < 96) {
        float s = part[t] + part[t + 96] + part[t + 192] + part[t + 288];
        esp[m * NATOM + jt * 96 + t] = (msk_s[jt * 96 + t] != 0.f) ? s : 0.f;
    }
}

// ============ one-time weight conversion to bf16 (+ rank-2 columns) ============
__global__ __launch_bounds__(256)
void wcvt_kernel(const float* __restrict__ W1, const float* __restrict__ W2,
                 const float* __restrict__ W3,
                 short* __restrict__ W1b, short* __restrict__ W2b,
                 short* __restrict__ W3b, float* __restrict__ w1q,
                 float* __restrict__ w1e)
{
    int i = blockIdx.x * 256 + threadIdx.x;
    if (i < 160 * 384) {
        int r = i / 384, cc = i % 384;
        W1b[i] = f2b(W1[(size_t)r * 386 + cc]);
    }
    int j = i - 160 * 384;
    if (j >= 0 && j < 128 * 160) W2b[j] = f2b(W2[j]);
    int k2 = j - 128 * 160;
    if (k2 >= 0 && k2 < 96 * 128) W3b[k2] = f2b(W3[k2]);
    if (i < 160) {
        w1q[i] = W1[(size_t)i * 386 + 384];
        w1e[i] = W1[(size_t)i * 386 + 385];
    }
}

extern "C" void kernel_launch(void* const* d_in, const int* in_sizes, int n_in,
                              void* d_out, int out_size, void* d_ws, size_t ws_size,
                              hipStream_t stream)
{
    const int*   species = (const int*)  d_in[0];
    const float* coords  = (const float*)d_in[1];
    const float* netq    = (const float*)d_in[2];
    const float* aev     = (const float*)d_in[3];
    const float* W1 = (const float*)d_in[4];
    const float* b1 = (const float*)d_in[5];
    const float* W2 = (const float*)d_in[6];
    const float* b2 = (const float*)d_in[7];
    const float* W3 = (const float*)d_in[8];
    const float* b3 = (const float*)d_in[9];
    const float* W4 = (const float*)d_in[10];
    const float* b4 = (const float*)d_in[11];

    float* q    = (float*)d_ws;                 // NN
    float* esp  = q + NN;                       // NN
    float* chi  = esp + NN;                     // NN
    float* w1q  = chi + NN;                     // 160
    float* w1e  = w1q + 160;                    // 160
    short* W1b  = (short*)(w1e + 160);          // 160*384
    short* W2b  = W1b + 160 * 384;              // 128*160
    short* W3b  = W2b + 128 * 160;              // 96*128
    short* h1p  = W3b + 96 * 128;               // NN*160 bf16

    // q = esp = 0 for iteration 0
    hipMemsetAsync(q, 0, 2 * (size_t)NN * sizeof(float), stream);
    wcvt_kernel<<<(160 * 384 + 128 * 160 + 96 * 128 + 255) / 256, 256, 0, stream>>>(
        W1, W2, W3, W1b, W2b, W3b, w1q, w1e);

    // iteration-invariant: h1p = aev @ W1[:, :384]^T + b1
    gemm0_k<160, 384><<<NN / 64, 256, 0, stream>>>(aev, W1b, b1, h1p);

    for (int it = 0; it < 4; ++it) {
        mlp23_kernel<<<NN / 64, 256, 0, stream>>>(
            h1p, W2b, b2, W3b, b3, W4, b4, q, esp, w1q, w1e, species, chi);
        if (it < 3)
            espd_kernel<true><<<dim3(NMOL, 4), 384, 0, stream>>>(
                chi, species, netq, coords, q, esp, nullptr);
        else
            espd_kernel<false><<<dim3(NMOL, 1), 384, 0, stream>>>(
                chi, species, netq, coords, q, esp, (float*)d_out);
    }
}

// Round 11
// 286.551 us; speedup vs baseline: 1.2923x; 1.2923x over previous
//
#include <hip/hip_runtime.h>
#include <math.h>

#define NMOL 256
#define NATOM 384
#define NN (NMOL*NATOM)          // 98304
#define A0C  0.529177249f
#define A0_INV (1.0f/0.529177249f)

typedef short bf16x8 __attribute__((ext_vector_type(8)));
typedef float f32x4  __attribute__((ext_vector_type(4)));

__constant__ float c_sigma[8] = {0.5515909f, 1.8886297f, 1.3225029f, 1.2316629f,
                                 2.1884933f, 1.7750372f, 1.3677907f, 1.3820058f};

__device__ __forceinline__ short f2b(float f) {           // f32 -> bf16 RNE
    unsigned u = __float_as_uint(f);
    u = (u + 0x7fffu + ((u >> 16) & 1u)) >> 16;
    return (short)u;
}
__device__ __forceinline__ float b2f(short s) {
    return __uint_as_float(((unsigned)(unsigned short)s) << 16);
}
// cheap celu(alpha=0.1): 0.1*(e^(10v)-1) = 0.1*exp2(10v*log2e)-0.1
__device__ __forceinline__ float celu01(float v) {
    float e = __builtin_amdgcn_exp2f(v * 14.426950408889634f);
    return v > 0.f ? v : fmaf(0.1f, e, -0.1f);
}
__device__ __forceinline__ bf16x8 cvt8(f32x4 a, f32x4 b) {
    bf16x8 r;
    r[0] = f2b(a.x); r[1] = f2b(a.y); r[2] = f2b(a.z); r[3] = f2b(a.w);
    r[4] = f2b(b.x); r[5] = f2b(b.y); r[6] = f2b(b.z); r[7] = f2b(b.w);
    return r;
}

// fast erf (x>=0): Abramowitz-Stegun 7.1.26, |abs err| <= 1.5e-7
__device__ __forceinline__ float erf_fast(float x) {
    float t = __builtin_amdgcn_rcpf(fmaf(0.3275911f, x, 1.0f));
    float p = fmaf(t, 1.061405429f, -1.453152027f);
    p = fmaf(t, p, 1.421413741f);
    p = fmaf(t, p, -0.284496736f);
    p = fmaf(t, p, 0.254829592f);
    p = p * t;
    float e = __builtin_amdgcn_exp2f(-x * x * 1.4426950408889634f);
    return fmaf(-p, e, 1.0f);
}

// ======================= GEMM0: h1p = aev @ W1a^T + b1 =======================
template<int N, int K>
__global__ __launch_bounds__(256, 4)
void gemm0_k(const float* __restrict__ A, const short* __restrict__ Bw,
             const float* __restrict__ bias, short* __restrict__ Cout)
{
    constexpr int NK = K / 32;
    constexpr int NF = N / 32;
    constexpr int N2 = N / 2;
    constexpr int AROW = 40, BROW = 40;
    constexpr int ASZ = 64 * AROW;
    constexpr int BSZ = N * BROW;
    constexpr int AB  = 2 * ASZ + 2 * BSZ;
    constexpr int CSZ = 64 * N;
    constexpr int SM  = AB > CSZ ? AB : CSZ;
    constexpr int NB  = (N * 4 + 255) / 256;

    __shared__ short smem[SM];
    short* As0 = smem;
    short* As1 = smem + ASZ;
    short* Bs0 = smem + 2 * ASZ;
    short* Bs1 = smem + 2 * ASZ + BSZ;
    short* Cs  = smem;

    const int t    = threadIdx.x;
    const int lane = t & 63;
    const int wave = t >> 6;
    const int wm   = wave >> 1, wn = wave & 1;
    const int l15  = lane & 15, l4 = lane >> 4;
    const int m0   = blockIdx.x * 64;
    const int arow = t >> 2, aseg = t & 3;
    const float* a_f32 = A + ((size_t)m0 + arow) * K + aseg * 8;

    f32x4 af0, af1;
    bf16x8 br[NB];

    auto loadA = [&](int k0) {
        af0 = *(const f32x4*)(a_f32 + k0);
        af1 = *(const f32x4*)(a_f32 + k0 + 4);
    };
    auto loadB = [&](int k0) {
        #pragma unroll
        for (int ci = 0; ci < NB; ++ci) {
            int c = ci * 256 + t;
            if ((N * 4) % 256 == 0 || c < N * 4) {
                int row = c >> 2, half = c & 3;
                br[ci] = *(const bf16x8*)(Bw + (size_t)row * K + k0 + half * 8);
            }
        }
    };
    auto writeA = [&](short* dst) {
        *(bf16x8*)&dst[arow * AROW + aseg * 8] = cvt8(af0, af1);
    };
    auto writeB = [&](short* dst) {
        #pragma unroll
        for (int ci = 0; ci < NB; ++ci) {
            int c = ci * 256 + t;
            if ((N * 4) % 256 == 0 || c < N * 4) {
                int row = c >> 2, half = c & 3;
                *(bf16x8*)&dst[row * BROW + half * 8] = br[ci];
            }
        }
    };

    f32x4 acc[2][NF] = {};

    loadA(0); loadB(0);
    writeA(As0); writeB(Bs0);
    __syncthreads();

    int cur = 0;
    for (int ks = 0; ks < NK; ++ks) {
        if (ks + 1 < NK) { loadA((ks + 1) * 32); loadB((ks + 1) * 32); }
        short* Ac = cur ? As1 : As0;
        short* Bc = cur ? Bs1 : Bs0;
        bf16x8 a[2];
        #pragma unroll
        for (int mf = 0; mf < 2; ++mf)
            a[mf] = *(const bf16x8*)&Ac[(wm * 32 + mf * 16 + l15) * AROW + l4 * 8];
        #pragma unroll
        for (int nf = 0; nf < NF; ++nf) {
            bf16x8 b = *(const bf16x8*)&Bc[(wn * N2 + nf * 16 + l15) * BROW + l4 * 8];
            #pragma unroll
            for (int mf = 0; mf < 2; ++mf)
                acc[mf][nf] = __builtin_amdgcn_mfma_f32_16x16x32_bf16(a[mf], b, acc[mf][nf], 0, 0, 0);
        }
        if (ks + 1 < NK) {
            writeA(cur ? As0 : As1);
            writeB(cur ? Bs0 : Bs1);
            __syncthreads();
            cur ^= 1;
        }
    }
    __syncthreads();

    #pragma unroll
    for (int nf = 0; nf < NF; ++nf) {
        int col = wn * N2 + nf * 16 + l15;
        float bc = bias[col];
        #pragma unroll
        for (int mf = 0; mf < 2; ++mf)
            #pragma unroll
            for (int r = 0; r < 4; ++r)
                Cs[(wm * 32 + mf * 16 + l4 * 4 + r) * N + col] = f2b(acc[mf][nf][r] + bc);
    }
    __syncthreads();
    #pragma unroll
    for (int i = 0; i < NF; ++i) {
        int c = i * 256 + t;
        *(bf16x8*)(Cout + (size_t)m0 * N + c * 8) = *(const bf16x8*)&Cs[c * 8];
    }
}

// ======================= fused layers 2+3+4, frag-direct (r7 structure) =======================
// A and B fragments loaded straight from global (rank-2 + celu applied in regs);
// only the stage-1->2 transpose (H2) lives in LDS. 3 barriers total.
// NOTE: __launch_bounds__(256,4) — (256,8) caps VGPR at 64 and SPILLS (r10 regression).
__global__ __launch_bounds__(256, 4)
void mlp23_kernel(const short* __restrict__ h1p, const short* __restrict__ W2b,
                  const float* __restrict__ b2, const short* __restrict__ W3b,
                  const float* __restrict__ b3, const float* __restrict__ W4,
                  const float* __restrict__ b4,
                  const float* __restrict__ qv, const float* __restrict__ espv,
                  const float* __restrict__ w1qp, const float* __restrict__ w1ep,
                  const int* __restrict__ species, float* __restrict__ chi)
{
    constexpr int K1 = 160, K2 = 128, N3 = 96;
    constexpr int H2ROW = 140;     // 280B stride -> ~2-way banks on b128 reads

    __shared__ short H2[64 * H2ROW];
    __shared__ float wq_s[K1], we_s[K1], w4_s[N3], b3_s[N3];
    __shared__ float chp[2][64];

    const int t    = threadIdx.x;
    const int lane = t & 63;
    const int wave = t >> 6;
    const int wm   = wave >> 1, wn = wave & 1;
    const int l15  = lane & 15, l4 = lane >> 4;
    const int m0   = blockIdx.x * 64;

    if (t < K1) { wq_s[t] = w1qp[t]; we_s[t] = w1ep[t]; }
    if (t < N3) { w4_s[t] = W4[t]; b3_s[t] = b3[t]; }

    // per-lane A-row constants (row = l15 within each mf group)
    int rowg[2];
    float qrow[2], erow[2];
    #pragma unroll
    for (int mf = 0; mf < 2; ++mf) {
        rowg[mf] = m0 + wm * 32 + mf * 16 + l15;
        qrow[mf] = qv[rowg[mf]];
        erow[mf] = espv[rowg[mf]];
    }
    __syncthreads();   // wq_s/we_s visible

    // ---- stage 1: celu(h1p + q*w1q + e*w1e) @ W2^T, K=160, no barriers ----
    f32x4 acc[2][4] = {};
    #pragma unroll
    for (int ks = 0; ks < 5; ++ks) {
        const int k0 = ks * 32 + l4 * 8;
        f32x4 wq0 = *(const f32x4*)&wq_s[k0];
        f32x4 wq1 = *(const f32x4*)&wq_s[k0 + 4];
        f32x4 we0 = *(const f32x4*)&we_s[k0];
        f32x4 we1 = *(const f32x4*)&we_s[k0 + 4];
        bf16x8 a[2];
        #pragma unroll
        for (int mf = 0; mf < 2; ++mf) {
            bf16x8 h = *(const bf16x8*)(h1p + (size_t)rowg[mf] * K1 + k0);
            #pragma unroll
            for (int j = 0; j < 4; ++j) {
                float v  = b2f(h[j])     + qrow[mf] * wq0[j] + erow[mf] * we0[j];
                float v2 = b2f(h[j + 4]) + qrow[mf] * wq1[j] + erow[mf] * we1[j];
                a[mf][j]     = f2b(celu01(v));
                a[mf][j + 4] = f2b(celu01(v2));
            }
        }
        #pragma unroll
        for (int nf = 0; nf < 4; ++nf) {
            bf16x8 b = *(const bf16x8*)(W2b + (size_t)(wn * 64 + nf * 16 + l15) * K1 + k0);
            #pragma unroll
            for (int mf = 0; mf < 2; ++mf)
                acc[mf][nf] = __builtin_amdgcn_mfma_f32_16x16x32_bf16(a[mf], b, acc[mf][nf], 0, 0, 0);
        }
    }

    // h2 tile -> LDS (celu applied)
    #pragma unroll
    for (int nf = 0; nf < 4; ++nf) {
        int col = wn * 64 + nf * 16 + l15;
        float bc = b2[col];
        #pragma unroll
        for (int mf = 0; mf < 2; ++mf)
            #pragma unroll
            for (int r = 0; r < 4; ++r)
                H2[(wm * 32 + mf * 16 + l4 * 4 + r) * H2ROW + col] =
                    f2b(celu01(acc[mf][nf][r] + bc));
    }
    __syncthreads();

    // ---- stage 2: H2 @ W3^T, K=128, B direct from global ----
    f32x4 acc2[2][3] = {};
    #pragma unroll
    for (int ks = 0; ks < 4; ++ks) {
        bf16x8 a[2];
        #pragma unroll
        for (int mf = 0; mf < 2; ++mf)
            a[mf] = *(const bf16x8*)&H2[(wm * 32 + mf * 16 + l15) * H2ROW + ks * 32 + l4 * 8];
        #pragma unroll
        for (int nf = 0; nf < 3; ++nf) {
            bf16x8 b = *(const bf16x8*)(W3b + (size_t)(wn * 48 + nf * 16 + l15) * K2 + ks * 32 + l4 * 8);
            #pragma unroll
            for (int mf = 0; mf < 2; ++mf)
                acc2[mf][nf] = __builtin_amdgcn_mfma_f32_16x16x32_bf16(a[mf], b, acc2[mf][nf], 0, 0, 0);
        }
    }

    // ---- chi epilogue: celu -> .W4 -> lane reduce -> softplus ----
    float val[2][4];
    #pragma unroll
    for (int mf = 0; mf < 2; ++mf)
        #pragma unroll
        for (int r = 0; r < 4; ++r) val[mf][r] = 0.f;
    #pragma unroll
    for (int nf = 0; nf < 3; ++nf) {
        int col = wn * 48 + nf * 16 + l15;
        float bc = b3_s[col];
        float wc = w4_s[col];
        #pragma unroll
        for (int mf = 0; mf < 2; ++mf)
            #pragma unroll
            for (int r = 0; r < 4; ++r)
                val[mf][r] += celu01(acc2[mf][nf][r] + bc) * wc;
    }
    #pragma unroll
    for (int off = 1; off < 16; off <<= 1)
        #pragma unroll
        for (int mf = 0; mf < 2; ++mf)
            #pragma unroll
            for (int r = 0; r < 4; ++r)
                val[mf][r] += __shfl_xor(val[mf][r], off, 64);
    if (l15 == 0) {
        #pragma unroll
        for (int mf = 0; mf < 2; ++mf)
            #pragma unroll
            for (int r = 0; r < 4; ++r)
                chp[wn][wm * 32 + mf * 16 + l4 * 4 + r] = val[mf][r];
    }
    __syncthreads();
    if (t < 64) {
        float s = chp[0][t] + chp[1][t] + b4[0];
        s = fmaxf(s, 0.f) + log1pf(expf(-fabsf(s)));   // softplus
        chi[m0 + t] = (species[m0 + t] != -1) ? s : 0.f;
    }
}

// ======= fused charge normalization + DIRECT ESP (no J matrix) =======
// DO_ESP: grid (NMOL, 4), block 384. Each block: charge-norm (redundant,
// cheap) -> full q vector in LDS -> thread (joff, iq) sums q_i*j_ij over a
// 96-i quarter for j = jt*96+joff -> 4 partials combined in LDS.
// !DO_ESP (final): grid (NMOL), writes output [species | q].
template<bool DO_ESP>
__global__ __launch_bounds__(384, 6)
void espd_kernel(const float* __restrict__ chi, const int* __restrict__ species,
                 const float* __restrict__ netq, const float* __restrict__ coords,
                 float* __restrict__ q, float* __restrict__ esp,
                 float* __restrict__ out)
{
    __shared__ float q_s[NATOM], msk_s[NATOM];
    __shared__ float cxs[NATOM], cys[NATOM], czs[NATOM], s2s[NATOM];
    __shared__ float part[NATOM];
    __shared__ float red_s[6], redc_s[6];

    const int m  = blockIdx.x, jt = blockIdx.y;
    const int t  = threadIdx.x;
    const int lane = t & 63, wv = t >> 6;
    const int idx = m * NATOM + t;

    float c = chi[idx];
    int sp = species[idx];
    float mk = (sp != -1) ? 1.f : 0.f;
    msk_s[t] = mk;
    if (DO_ESP) {
        cxs[t] = coords[(size_t)idx * 3 + 0];
        cys[t] = coords[(size_t)idx * 3 + 1];
        czs[t] = coords[(size_t)idx * 3 + 2];
        float sig = c_sigma[sp < 0 ? 7 : sp];
        s2s[t] = sig * sig;
    }
    // block reduce chi & mask
    float sc = c, sm = mk;
    #pragma unroll
    for (int off = 1; off < 64; off <<= 1) {
        sc += __shfl_xor(sc, off, 64);
        sm += __shfl_xor(sm, off, 64);
    }
    if (lane == 0) { red_s[wv] = sc; redc_s[wv] = sm; }
    __syncthreads();
    float chi_sum = red_s[0] + red_s[1] + red_s[2] + red_s[3] + red_s[4] + red_s[5];
    float na      = redc_s[0] + redc_s[1] + redc_s[2] + redc_s[3] + redc_s[4] + redc_s[5];
    float Q = netq[m];
    float k_net = 1.f + fabsf(Q) / chi_sum;
    float chi_mean = chi_sum / na;
    float k_p = (Q > 0.f) ? k_net : 1.f;
    float k_n = (Q < 0.f) ? k_net : 1.f;
    float qj = (-k_n * c + k_p * chi_mean) * mk;

    if (!DO_ESP) {
        out[idx]      = (float)sp;
        out[NN + idx] = qj;
        return;
    }

    q_s[t] = qj;
    if (jt == 0) q[idx] = qj;        // global q for next iteration's features
    __syncthreads();

    // ESP: j = jt*96 + joff, this thread sums i in [iq*96, iq*96+96)
    const int joff = t % 96;
    const int iq   = t / 96;
    const int jj   = jt * 96 + joff;
    const float rx = cxs[jj], ry = cys[jj], rz = czs[jj], s2j = s2s[jj];
    float acc = 0.f;
    const int i0 = iq * 96;
    #pragma unroll 4
    for (int i = i0; i < i0 + 96; ++i) {
        float dx = cxs[i] - rx, dy = cys[i] - ry, dz = czs[i] - rz;
        float d2 = fmaf(dx, dx, fmaf(dy, dy, dz * dz)) + 1e-16f;
        float rs = __builtin_amdgcn_rsqf(d2);
        float d  = d2 * rs * A0_INV;
        float ss = fmaxf(s2s[i] + s2j, 1e-8f);
        float x  = d * __builtin_amdgcn_rsqf(2.f * ss);
        float v  = erf_fast(x) * rs * A0C;
        acc += (i == jj) ? 0.f : q_s[i] * v;
    }
    part[t] = acc;
    __syncthreads();
    if (t < 96) {
        float s = part[t] + part[t + 96] + part[t + 192] + part[t + 288];
        esp[m * NATOM + jt * 96 + t] = (msk_s[jt * 96 + t] != 0.f) ? s : 0.f;
    }
}

// ============ one-time weight conversion to bf16 (+ rank-2 columns) ============
__global__ __launch_bounds__(256)
void wcvt_kernel(const float* __restrict__ W1, const float* __restrict__ W2,
                 const float* __restrict__ W3,
                 short* __restrict__ W1b, short* __restrict__ W2b,
                 short* __restrict__ W3b, float* __restrict__ w1q,
                 float* __restrict__ w1e)
{
    int i = blockIdx.x * 256 + threadIdx.x;
    if (i < 160 * 384) {
        int r = i / 384, cc = i % 384;
        W1b[i] = f2b(W1[(size_t)r * 386 + cc]);
    }
    int j = i - 160 * 384;
    if (j >= 0 && j < 128 * 160) W2b[j] = f2b(W2[j]);
    int k2 = j - 128 * 160;
    if (k2 >= 0 && k2 < 96 * 128) W3b[k2] = f2b(W3[k2]);
    if (i < 160) {
        w1q[i] = W1[(size_t)i * 386 + 384];
        w1e[i] = W1[(size_t)i * 386 + 385];
    }
}

extern "C" void kernel_launch(void* const* d_in, const int* in_sizes, int n_in,
                              void* d_out, int out_size, void* d_ws, size_t ws_size,
                              hipStream_t stream)
{
    const int*   species = (const int*)  d_in[0];
    const float* coords  = (const float*)d_in[1];
    const float* netq    = (const float*)d_in[2];
    const float* aev     = (const float*)d_in[3];
    const float* W1 = (const float*)d_in[4];
    const float* b1 = (const float*)d_in[5];
    const float* W2 = (const float*)d_in[6];
    const float* b2 = (const float*)d_in[7];
    const float* W3 = (const float*)d_in[8];
    const float* b3 = (const float*)d_in[9];
    const float* W4 = (const float*)d_in[10];
    const float* b4 = (const float*)d_in[11];

    float* q    = (float*)d_ws;                 // NN
    float* esp  = q + NN;                       // NN
    float* chi  = esp + NN;                     // NN
    float* w1q  = chi + NN;                     // 160
    float* w1e  = w1q + 160;                    // 160
    short* W1b  = (short*)(w1e + 160);          // 160*384
    short* W2b  = W1b + 160 * 384;              // 128*160
    short* W3b  = W2b + 128 * 160;              // 96*128
    short* h1p  = W3b + 96 * 128;               // NN*160 bf16

    // q = esp = 0 for iteration 0
    hipMemsetAsync(q, 0, 2 * (size_t)NN * sizeof(float), stream);
    wcvt_kernel<<<(160 * 384 + 128 * 160 + 96 * 128 + 255) / 256, 256, 0, stream>>>(
        W1, W2, W3, W1b, W2b, W3b, w1q, w1e);

    // iteration-invariant: h1p = aev @ W1[:, :384]^T + b1
    gemm0_k<160, 384><<<NN / 64, 256, 0, stream>>>(aev, W1b, b1, h1p);

    for (int it = 0; it < 4; ++it) {
        mlp23_kernel<<<NN / 64, 256, 0, stream>>>(
            h1p, W2b, b2, W3b, b3, W4, b4, q, esp, w1q, w1e, species, chi);
        if (it < 3)
            espd_kernel<true><<<dim3(NMOL, 4), 384, 0, stream>>>(
                chi, species, netq, coords, q, esp, nullptr);
        else
            espd_kernel<false><<<dim3(NMOL, 1), 384, 0, stream>>>(
                chi, species, netq, coords, q, esp, (float*)d_out);
    }
}